// Round 2
// baseline (553.860 us; speedup 1.0000x reference)
//
#include <hip/hip_runtime.h>
#include <hip/hip_bf16.h>
#include <math.h>

// DecoderSphere: B=16, T=65536, D=32, H=W=64. One thread per point.
// Round 2: (a) weights staged in LDS (rounded to bf16 precision) -> kills the
// s_load stall; (b) activations rounded to bf16 before each matmul to probe
// MFMA numerics while still computing in fp32 FMAs.

#define ND 32

static __device__ __forceinline__ float rb(float x) {
    // round-to-nearest-even to bf16, back to f32 (simulates MFMA input rounding)
    return __bfloat162float(__float2bfloat16(x));
}

__global__ __launch_bounds__(256, 3) void decoder_sphere_kernel(
    const float* __restrict__ p,
    const float* __restrict__ c,
    const float* __restrict__ fc_p_w,
    const float* __restrict__ fc_p_b,
    const float* __restrict__ w0,
    const float* __restrict__ b0,
    const float* __restrict__ w1,
    const float* __restrict__ b1,
    const float* __restrict__ fc_out_w,
    const float* __restrict__ fc_out_b,
    float* __restrict__ out)
{
    const float PI_F = 3.1415927410125732f;

    // ---- stage w0 (5120 f32) + w1 (5120 f32) into LDS, rounded to bf16 ----
    __shared__ float sw[10240];   // [0,5120): w0[i][d][j]; [5120,10240): w1[i][j][d]
#pragma unroll
    for (int t = 0; t < 10; ++t) {
        const int idx = (t * 256 + threadIdx.x) * 4;
        const float* src = (idx < 5120) ? (w0 + idx) : (w1 + (idx - 5120));
        float4 v = *(const float4*)src;
        v.x = rb(v.x); v.y = rb(v.y); v.z = rb(v.z); v.w = rb(v.w);
        *(float4*)&sw[idx] = v;
    }
    __syncthreads();

    const int g = blockIdx.x * blockDim.x + threadIdx.x;   // 0 .. B*T-1
    const int b = g >> 16;                                  // T = 65536

    // ---- load point ----
    const float px = p[3 * g + 0];
    const float py = p[3 * g + 1];
    const float pz = p[3 * g + 2];

    // ---- sphere interp (faithful port incl. quirks) ----
    const float lat = 90.0f - (atan2f(pz, sqrtf(px * px + py * py)) * 180.0f) / PI_F;
    const float mer = fmodf(360.0f + (atan2f(py, px) * 180.0f) / PI_F, 360.0f);

    const int xg = (int)floorf(mer / 5.625f);   // [0,63]
    const int yg = (int)floorf(lat / 2.8125f);  // [0,64]

    const int xl = (xg + 63) & 63;
    const int xr = (xg + 1) & 63;
    const int ylo = yg - 1 - ((yg - 1) >> 6);
    const int yhi = yg + 1 - ((yg + 1) >> 6);

    const float dx = (float)(xr - xg);          // 1 normally, -63 at wrap
    const float dy = (float)(yhi - yg);         // 1 normally, 0 at south edge

    const int yloi = ylo < 63 ? ylo : 63;       // JAX clamps OOB gathers
    const int yhii = yhi < 63 ? yhi : 63;

    const float w11 = dx * dy;
    const float w12 = (1.0f - dx) * dy;
    const float w21 = dx * (1.0f - dy);
    const float w22 = (1.0f - dx) * (1.0f - dy);

    const float* gb  = c + (size_t)b * (64 * 64 * ND);
    const float* r11 = gb + (xl * 64 + yloi) * ND;
    const float* r12 = gb + (xr * 64 + yloi) * ND;
    const float* r21 = gb + (xl * 64 + yhii) * ND;
    const float* r22 = gb + (xr * 64 + yhii) * ND;

    float cf[ND];
#pragma unroll
    for (int d = 0; d < ND; d += 4) {
        const float4 a  = *(const float4*)(r11 + d);
        const float4 e  = *(const float4*)(r12 + d);
        const float4 f  = *(const float4*)(r21 + d);
        const float4 h4 = *(const float4*)(r22 + d);
        cf[d + 0] = w11 * a.x + w12 * e.x + w21 * f.x + w22 * h4.x;
        cf[d + 1] = w11 * a.y + w12 * e.y + w21 * f.y + w22 * h4.y;
        cf[d + 2] = w11 * a.z + w12 * e.z + w21 * f.z + w22 * h4.z;
        cf[d + 3] = w11 * a.w + w12 * e.w + w21 * f.w + w22 * h4.w;
    }

    // ---- net = p @ fc_p_w + fc_p_b  (fp32, matches planned MFMA design) ----
    float net[ND];
#pragma unroll
    for (int d = 0; d < ND; ++d) {
        net[d] = fmaf(px, fc_p_w[d],
                 fmaf(py, fc_p_w[ND + d],
                 fmaf(pz, fc_p_w[2 * ND + d], fc_p_b[d])));
    }

    // ---- 5 resnet blocks; weights from LDS (bf16-rounded), activations
    //      rounded to bf16 before each matmul, accumulation fp32 ----
    for (int i = 0; i < 5; ++i) {
        const float* W0 = &sw[i * ND * ND];          // w0[i][d][j]
        const float* W1 = &sw[5120 + i * ND * ND];   // w1[i][j][d]
        const float* B0 = b0 + i * ND;
        const float* B1 = b1 + i * ND;

#pragma unroll
        for (int d = 0; d < ND; ++d) net[d] += cf[d];

        float h[ND];
#pragma unroll
        for (int j = 0; j < ND; ++j) h[j] = B0[j];

#pragma unroll
        for (int d = 0; d < ND; ++d) {
            const float rn = rb(fmaxf(net[d], 0.0f));   // bf16 input to matmul1
            const float4* wrow = (const float4*)&W0[d * ND];
#pragma unroll
            for (int jj = 0; jj < ND / 4; ++jj) {
                const float4 w = wrow[jj];
                h[4 * jj + 0] = fmaf(rn, w.x, h[4 * jj + 0]);
                h[4 * jj + 1] = fmaf(rn, w.y, h[4 * jj + 1]);
                h[4 * jj + 2] = fmaf(rn, w.z, h[4 * jj + 2]);
                h[4 * jj + 3] = fmaf(rn, w.w, h[4 * jj + 3]);
            }
        }

#pragma unroll
        for (int j = 0; j < ND; ++j) {
            const float hj = rb(fmaxf(h[j], 0.0f));     // bf16 input to matmul2
            const float4* wrow = (const float4*)&W1[j * ND];
#pragma unroll
            for (int dd = 0; dd < ND / 4; ++dd) {
                const float4 w = wrow[dd];
                net[4 * dd + 0] = fmaf(hj, w.x, net[4 * dd + 0]);
                net[4 * dd + 1] = fmaf(hj, w.y, net[4 * dd + 1]);
                net[4 * dd + 2] = fmaf(hj, w.z, net[4 * dd + 2]);
                net[4 * dd + 3] = fmaf(hj, w.w, net[4 * dd + 3]);
            }
        }

#pragma unroll
        for (int d = 0; d < ND; ++d) net[d] += B1[d];
    }

    // ---- out = relu(net) @ fc_out_w + fc_out_b  (fp32) ----
    float acc = fc_out_b[0];
#pragma unroll
    for (int d = 0; d < ND; ++d)
        acc = fmaf(fmaxf(net[d], 0.0f), fc_out_w[d], acc);

    out[g] = acc;
}

extern "C" void kernel_launch(void* const* d_in, const int* in_sizes, int n_in,
                              void* d_out, int out_size, void* d_ws, size_t ws_size,
                              hipStream_t stream) {
    const float* p        = (const float*)d_in[0];
    const float* c        = (const float*)d_in[2];
    const float* fc_p_w   = (const float*)d_in[4];
    const float* fc_p_b   = (const float*)d_in[5];
    const float* w0       = (const float*)d_in[6];
    const float* b0       = (const float*)d_in[7];
    const float* w1       = (const float*)d_in[8];
    const float* b1       = (const float*)d_in[9];
    const float* fc_out_w = (const float*)d_in[10];
    const float* fc_out_b = (const float*)d_in[11];
    float* out = (float*)d_out;

    const int total = 16 * 65536;
    dim3 block(256);
    dim3 grid(total / 256);
    hipLaunchKernelGGL(decoder_sphere_kernel, grid, block, 0, stream,
                       p, c, fc_p_w, fc_p_b, w0, b0, w1, b1,
                       fc_out_w, fc_out_b, out);
}

// Round 3
// 209.882 us; speedup vs baseline: 2.6389x; 2.6389x over previous
//
#include <hip/hip_runtime.h>
#include <hip/hip_bf16.h>
#include <math.h>

// DecoderSphere B=16,T=65536,D=32. MFMA bf16 restructure.
// All matmuls computed transposed: D[feat][pt] = W^T[feat][k] * X^T[k][pt].
//  - A operand = W^T frags (register-resident, 5 layers x {w0,w1} x 2 feat-halves)
//  - B operand = activations, LDS [pt][32 bf16] rows -> one ds_read_b128
//  - C/D: col=lane&15=pt, row=quad*4+reg=feat -> transform write = ds_write_b64
// Wave-private LDS buffers -> no __syncthreads in the main loop.

typedef __attribute__((ext_vector_type(8))) short short8;
typedef __attribute__((ext_vector_type(4))) float f32x4;

#define CFW 36   // cf row stride in dwords (32 + 4 pad, keeps b128 4-dword aligned)
#define AW  20   // activation row stride in dwords (16 + 4 pad)

static __device__ __forceinline__ unsigned short f2bf(float x) {
    __hip_bfloat16 b = __float2bfloat16(x);
    unsigned short u;
    __builtin_memcpy(&u, &b, 2);
    return u;
}

__global__ __launch_bounds__(256, 2) void decoder_mfma(
    const float* __restrict__ p,
    const float* __restrict__ c,
    const float* __restrict__ fc_p_w,
    const float* __restrict__ fc_p_b,
    const float* __restrict__ w0g,
    const float* __restrict__ b0g,
    const float* __restrict__ w1g,
    const float* __restrict__ b1g,
    const float* __restrict__ fc_out_w,
    const float* __restrict__ fc_out_b,
    float* __restrict__ out)
{
    __shared__ float lds[13056];   // 52224 B
    const int tid  = threadIdx.x;
    const int wave = tid >> 6;
    const int lane = tid & 63;
    const int m15  = lane & 15;
    const int q    = lane >> 4;

    float* cfb = lds + wave * 2304;          // [64 pts][36]  f32 cf
    float* act = lds + 9216 + wave * 640;    // 2 bufs x [16 pts][20]
    float* spb = lds + 11776 + wave * 192;   // [3][64] p coords
    float* cb  = lds + 12544;                // constants [512]

    // ---- stage constants into LDS (once per block) ----
    // [0,96): fc_p_w  [96,128): fc_p_b  [128,288): b0  [288,448): b1
    // [448,480): fc_out_w  [480]: fc_out_b
    for (int t = tid; t < 481; t += 256) {
        float v;
        if      (t < 96)  v = fc_p_w[t];
        else if (t < 128) v = fc_p_b[t - 96];
        else if (t < 288) v = b0g[t - 128];
        else if (t < 448) v = b1g[t - 288];
        else if (t < 480) v = fc_out_w[t - 448];
        else              v = fc_out_b[0];
        cb[t] = v;
    }

    // ---- weight A-fragments (W^T), register-resident ----
    // A[m][k] = W[k][16h+m]; lane: m=lane&15, k=8q+j  (j packed pairwise)
    short8 wf[5][2][2];   // [layer][0=w0,1=w1][feat-half]
#pragma unroll
    for (int i = 0; i < 5; ++i) {
#pragma unroll
        for (int h = 0; h < 2; ++h) {
            const int base = i * 1024 + 16 * h + m15;
            short8 a0, a1;
#pragma unroll
            for (int j = 0; j < 8; ++j) {
                a0[j] = (short)f2bf(w0g[base + (8 * q + j) * 32]);
                a1[j] = (short)f2bf(w1g[base + (8 * q + j) * 32]);
            }
            wf[i][0][h] = a0;
            wf[i][1][h] = a1;
        }
    }

    __syncthreads();   // constants visible (only barrier in the kernel)

    // ================= phase 1: per-lane interp (64 pts/wave) =================
    const float PI_F = 3.1415927410125732f;
    const int g = blockIdx.x * 256 + tid;
    const int b = g >> 16;                      // T = 65536

    const float px = p[3 * g + 0];
    const float py = p[3 * g + 1];
    const float pz = p[3 * g + 2];

    const float lat = 90.0f - (atan2f(pz, sqrtf(px * px + py * py)) * 180.0f) / PI_F;
    const float mer = fmodf(360.0f + (atan2f(py, px) * 180.0f) / PI_F, 360.0f);

    const int xg = (int)floorf(mer / 5.625f);
    const int yg = (int)floorf(lat / 2.8125f);

    const int xl = (xg + 63) & 63;
    const int xr = (xg + 1) & 63;
    const int ylo = yg - 1 - ((yg - 1) >> 6);
    const int yhi = yg + 1 - ((yg + 1) >> 6);

    const float dx = (float)(xr - xg);
    const float dy = (float)(yhi - yg);

    const int yloi = ylo < 63 ? ylo : 63;
    const int yhii = yhi < 63 ? yhi : 63;

    const float w11 = dx * dy;
    const float w12 = (1.0f - dx) * dy;
    const float w21 = dx * (1.0f - dy);
    const float w22 = (1.0f - dx) * (1.0f - dy);

    const float* gb  = c + (size_t)b * (64 * 64 * 32);
    const float* r11 = gb + (xl * 64 + yloi) * 32;
    const float* r12 = gb + (xr * 64 + yloi) * 32;
    const float* r21 = gb + (xl * 64 + yhii) * 32;
    const float* r22 = gb + (xr * 64 + yhii) * 32;

    spb[lane]       = px;
    spb[64 + lane]  = py;
    spb[128 + lane] = pz;

    float* cfr = cfb + lane * CFW;
#pragma unroll
    for (int d = 0; d < 32; d += 4) {
        const f32x4 a  = *(const f32x4*)(r11 + d);
        const f32x4 e  = *(const f32x4*)(r12 + d);
        const f32x4 f  = *(const f32x4*)(r21 + d);
        const f32x4 h4 = *(const f32x4*)(r22 + d);
        f32x4 v = w11 * a + w12 * e + w21 * f + w22 * h4;
        *(f32x4*)(cfr + d) = v;
    }

    __builtin_amdgcn_wave_barrier();   // keep phase-1 writes before phase-2 reads

    // ================= phase 2: 4 tiles of 16 points =================
#pragma unroll 1
    for (int t = 0; t < 4; ++t) {
        const int ptl = t * 16 + m15;           // wave-local point = B-frag col
        const float qx = spb[ptl];
        const float qy = spb[64 + ptl];
        const float qz = spb[128 + ptl];

        f32x4 net[2], cf[2];
#pragma unroll
        for (int h = 0; h < 2; ++h) {
            const int fo = 16 * h + 4 * q;      // this lane's 4 feats (rows)
            const f32x4 wx = *(const f32x4*)(cb + fo);
            const f32x4 wy = *(const f32x4*)(cb + 32 + fo);
            const f32x4 wz = *(const f32x4*)(cb + 64 + fo);
            const f32x4 bb = *(const f32x4*)(cb + 96 + fo);
            net[h] = qx * wx + qy * wy + qz * wz + bb;
            cf[h]  = *(const f32x4*)(cfb + ptl * CFW + fo);
        }

        float* buf0 = act;
        float* buf1 = act + 320;

#pragma unroll
        for (int i = 0; i < 5; ++i) {
            // net += cf ; X = relu(net) -> bf16 -> LDS [pt][feat]
#pragma unroll
            for (int h = 0; h < 2; ++h) {
                net[h] += cf[h];
                const f32x4 x = net[h];
                const unsigned d0 = (unsigned)f2bf(fmaxf(x[0], 0.f)) |
                                    ((unsigned)f2bf(fmaxf(x[1], 0.f)) << 16);
                const unsigned d1 = (unsigned)f2bf(fmaxf(x[2], 0.f)) |
                                    ((unsigned)f2bf(fmaxf(x[3], 0.f)) << 16);
                unsigned* wp = (unsigned*)buf0 + m15 * AW + h * 8 + 2 * q;
                wp[0] = d0;
                wp[1] = d1;
            }
            __builtin_amdgcn_wave_barrier();
            const short8 xf = *(const short8*)(buf0 + m15 * AW + 4 * q);

            const int b0o = 128 + i * 32 + 4 * q;
            f32x4 hacc0 = __builtin_amdgcn_mfma_f32_16x16x32_bf16(
                wf[i][0][0], xf, *(const f32x4*)(cb + b0o), 0, 0, 0);
            f32x4 hacc1 = __builtin_amdgcn_mfma_f32_16x16x32_bf16(
                wf[i][0][1], xf, *(const f32x4*)(cb + b0o + 16), 0, 0, 0);

            // H = relu(hacc) -> bf16 -> LDS
#pragma unroll
            for (int h = 0; h < 2; ++h) {
                const f32x4 x = (h == 0) ? hacc0 : hacc1;
                const unsigned d0 = (unsigned)f2bf(fmaxf(x[0], 0.f)) |
                                    ((unsigned)f2bf(fmaxf(x[1], 0.f)) << 16);
                const unsigned d1 = (unsigned)f2bf(fmaxf(x[2], 0.f)) |
                                    ((unsigned)f2bf(fmaxf(x[3], 0.f)) << 16);
                unsigned* wp = (unsigned*)buf1 + m15 * AW + h * 8 + 2 * q;
                wp[0] = d0;
                wp[1] = d1;
            }
            __builtin_amdgcn_wave_barrier();
            const short8 hf = *(const short8*)(buf1 + m15 * AW + 4 * q);

            net[0] = __builtin_amdgcn_mfma_f32_16x16x32_bf16(wf[i][1][0], hf, net[0], 0, 0, 0);
            net[1] = __builtin_amdgcn_mfma_f32_16x16x32_bf16(wf[i][1][1], hf, net[1], 0, 0, 0);

            const int b1o = 288 + i * 32 + 4 * q;
            net[0] += *(const f32x4*)(cb + b1o);
            net[1] += *(const f32x4*)(cb + b1o + 16);
        }

        // epilogue: out[pt] = sum_feat relu(net)*fc_out_w + fc_out_b
        const f32x4 ow0 = *(const f32x4*)(cb + 448 + 4 * q);
        const f32x4 ow1 = *(const f32x4*)(cb + 448 + 16 + 4 * q);
        float s = 0.f;
#pragma unroll
        for (int r = 0; r < 4; ++r)
            s += fmaxf(net[0][r], 0.f) * ow0[r] + fmaxf(net[1][r], 0.f) * ow1[r];
        s += __shfl_xor(s, 16, 64);
        s += __shfl_xor(s, 32, 64);
        if (q == 0)
            out[blockIdx.x * 256 + wave * 64 + ptl] = s + cb[480];
    }
}

extern "C" void kernel_launch(void* const* d_in, const int* in_sizes, int n_in,
                              void* d_out, int out_size, void* d_ws, size_t ws_size,
                              hipStream_t stream) {
    const float* p        = (const float*)d_in[0];
    const float* c        = (const float*)d_in[2];
    const float* fc_p_w   = (const float*)d_in[4];
    const float* fc_p_b   = (const float*)d_in[5];
    const float* w0       = (const float*)d_in[6];
    const float* b0       = (const float*)d_in[7];
    const float* w1       = (const float*)d_in[8];
    const float* b1       = (const float*)d_in[9];
    const float* fc_out_w = (const float*)d_in[10];
    const float* fc_out_b = (const float*)d_in[11];
    float* out = (float*)d_out;

    dim3 block(256);
    dim3 grid((16 * 65536) / 256);   // 4096 blocks
    hipLaunchKernelGGL(decoder_mfma, grid, block, 0, stream,
                       p, c, fc_p_w, fc_p_b, w0, b0, w1, b1,
                       fc_out_w, fc_out_b, out);
}